// Round 3
// baseline (761.930 us; speedup 1.0000x reference)
//
#include <hip/hip_runtime.h>

#define N_NODES 50000
#define N_EDGES 600000
#define DIM     128

typedef __attribute__((ext_vector_type(8))) short short8b;  // 8 bf16
typedef __attribute__((ext_vector_type(4))) float f32x4;

__device__ inline unsigned short f2bf(float f) {
    unsigned int u = __builtin_bit_cast(unsigned int, f);
    unsigned int r = (u + 0x7FFFu + ((u >> 16) & 1u)) >> 16;
    return (unsigned short)r;
}
__device__ inline float bf2f(unsigned short b) {
    unsigned int u = ((unsigned int)b) << 16;
    return __builtin_bit_cast(float, u);
}

// ---------------------------------------------------------------------------
// CSR build
// ---------------------------------------------------------------------------
__global__ void deg_hist_kernel(const int* __restrict__ dst, int* __restrict__ deg) {
    int e = blockIdx.x * blockDim.x + threadIdx.x;
    if (e < N_EDGES) atomicAdd(&deg[dst[e]], 1);
}

__global__ __launch_bounds__(1024) void scan_kernel(const int* __restrict__ deg,
                                                    int* __restrict__ rowptr) {
    __shared__ int part[1024];
    const int CH = (N_NODES + 1023) / 1024;  // 49
    int t = threadIdx.x;
    int start = t * CH;
    int end   = min(start + CH, N_NODES);
    int s = 0;
    for (int i = start; i < end; i++) s += deg[i];
    part[t] = s;
    __syncthreads();
    for (int off = 1; off < 1024; off <<= 1) {
        int u = (t >= off) ? part[t - off] : 0;
        __syncthreads();
        part[t] += u;
        __syncthreads();
    }
    int run = part[t] - s;  // exclusive prefix
    for (int i = start; i < end; i++) {
        rowptr[i] = run;
        run += deg[i];
    }
    if (t == 1023) rowptr[N_NODES] = run;
}

__global__ void fill_kernel(const int* __restrict__ src, const int* __restrict__ dst,
                            const int* __restrict__ rowptr, int* __restrict__ cursor,
                            int* __restrict__ csr_src) {
    int e = blockIdx.x * blockDim.x + threadIdx.x;
    if (e >= N_EDGES) return;
    int d = dst[e];
    int pos = rowptr[d] + atomicAdd(&cursor[d], 1);
    csr_src[pos] = src[e];
}

// ---------------------------------------------------------------------------
// x (fp32) -> bf16
// ---------------------------------------------------------------------------
__global__ void convert_x_kernel(const float* __restrict__ x, unsigned short* __restrict__ xb) {
    int i = blockIdx.x * blockDim.x + threadIdx.x;  // 4 elems/thread
    const float4 v = *(const float4*)&x[(size_t)i * 4];
    ushort4 o;
    o.x = f2bf(v.x); o.y = f2bf(v.y); o.z = f2bf(v.z); o.w = f2bf(v.w);
    *(ushort4*)&xb[(size_t)i * 4] = o;
}

// ---------------------------------------------------------------------------
// Weight prep: Bt_hi/Bt_lo [4][128 cols][256 k] bf16, where the 256-k axis is
// [Wl rows | Wr rows] stacked, transposed so a B-fragment read is contiguous.
// W = hi + lo (hi = bf16 round of W, lo = bf16 round of residual).
// ---------------------------------------------------------------------------
__global__ void prep_w_kernel(const float* __restrict__ Wl, const float* __restrict__ Wr,
                              unsigned short* __restrict__ Bt_hi,
                              unsigned short* __restrict__ Bt_lo) {
    int idx = blockIdx.x * blockDim.x + threadIdx.x;  // 4*256*128 total
    if (idx >= 4 * 256 * 128) return;
    int l = idx >> 15;            // /(256*128)
    int rem = idx & 32767;
    int k = rem >> 7;             // 0..255
    int c = rem & 127;
    float w = (k < 128) ? Wl[l * 16384 + k * 128 + c]
                        : Wr[l * 16384 + (k - 128) * 128 + c];
    unsigned short hi = f2bf(w);
    float res = w - bf2f(hi);
    unsigned short lo = f2bf(res);
    int out = l * 32768 + c * 256 + k;
    Bt_hi[out] = hi;
    Bt_lo[out] = lo;
}

// ---------------------------------------------------------------------------
// Fused SAGEConv layer. Block = 256 threads (4 waves), BM = 64 rows.
// Phase 1: gather bf16 neighbor rows (fp32 accum), scale, pack [agg|h] into
//          padded LDS A-tile (row stride 264 ushorts -> 2-way bank conflicts).
// Phase 2: MFMA GEMM [64x256] x [256x128]: wave w owns 16-row tile, loops
//          8 col-tiles; B hi/lo fragments streamed from L2.
// ---------------------------------------------------------------------------
__global__ __launch_bounds__(256) void sage_layer_kernel(
    const int* __restrict__ rowptr, const int* __restrict__ csr_src,
    const unsigned short* __restrict__ hin,
    const unsigned short* __restrict__ Bt_hi, const unsigned short* __restrict__ Bt_lo,
    const float* __restrict__ bias,
    unsigned short* __restrict__ hout_bf, float* __restrict__ hout_f32, int final_layer) {
    __shared__ unsigned short s_A[64][264];
    int t = threadIdx.x;
    int row0 = blockIdx.x * 64;

    // --- gather phase: 8 groups x 32 lanes, 8 sub-batches ---
    {
        int g     = t >> 5;         // 0..7
        int lane5 = t & 31;         // 0..31, handles dims 4*lane5..+3
        int d4    = lane5 << 2;
        for (int s8 = 0; s8 < 64; s8 += 8) {
            int tr = s8 + g;
            int node = row0 + tr;
            if (node < N_NODES) {
                int beg = rowptr[node], end = rowptr[node + 1];
                float a0 = 0.f, a1 = 0.f, a2 = 0.f, a3 = 0.f;
                for (int i = beg; i < end; i++) {
                    int s = csr_src[i];
                    const ushort4 v = *(const ushort4*)&hin[(size_t)s * DIM + d4];
                    a0 += bf2f(v.x); a1 += bf2f(v.y); a2 += bf2f(v.z); a3 += bf2f(v.w);
                }
                float scale = 1.0f / fmaxf((float)(end - beg), 1.0f);
                ushort4 o;
                o.x = f2bf(a0 * scale); o.y = f2bf(a1 * scale);
                o.z = f2bf(a2 * scale); o.w = f2bf(a3 * scale);
                *(ushort4*)&s_A[tr][d4] = o;
                *(ushort4*)&s_A[tr][128 + d4] = *(const ushort4*)&hin[(size_t)node * DIM + d4];
            } else {
                ushort4 z = { 0, 0, 0, 0 };
                *(ushort4*)&s_A[tr][d4] = z;
                *(ushort4*)&s_A[tr][128 + d4] = z;
            }
        }
    }
    __syncthreads();

    // --- MFMA GEMM phase ---
    int lane = t & 63;
    int w    = t >> 6;              // wave 0..3 -> rows w*16..+15
    int r16  = lane & 15;
    int kg   = lane >> 4;           // 0..3
    f32x4 acc[8];
    #pragma unroll
    for (int ct = 0; ct < 8; ct++) acc[ct] = (f32x4){0.f, 0.f, 0.f, 0.f};

    #pragma unroll
    for (int kk = 0; kk < 8; kk++) {
        int k = kk * 32 + kg * 8;
        short8b a = *(const short8b*)&s_A[w * 16 + r16][k];
        #pragma unroll
        for (int ct = 0; ct < 8; ct++) {
            const size_t boff = (size_t)(ct * 16 + r16) * 256 + k;
            short8b bh = *(const short8b*)&Bt_hi[boff];
            short8b bl = *(const short8b*)&Bt_lo[boff];
            acc[ct] = __builtin_amdgcn_mfma_f32_16x16x32_bf16(a, bh, acc[ct], 0, 0, 0);
            acc[ct] = __builtin_amdgcn_mfma_f32_16x16x32_bf16(a, bl, acc[ct], 0, 0, 0);
        }
    }

    // --- epilogue: bias + ReLU, write bf16 (or fp32 for final layer) ---
    #pragma unroll
    for (int ct = 0; ct < 8; ct++) {
        int col = ct * 16 + r16;
        float bb = bias[col];
        #pragma unroll
        for (int j = 0; j < 4; j++) {
            int grow = row0 + w * 16 + kg * 4 + j;
            if (grow < N_NODES) {
                float v = fmaxf(acc[ct][j] + bb, 0.f);
                if (final_layer) hout_f32[(size_t)grow * DIM + col] = v;
                else             hout_bf [(size_t)grow * DIM + col] = f2bf(v);
            }
        }
    }
}

// ---------------------------------------------------------------------------
// Launch
// ---------------------------------------------------------------------------
extern "C" void kernel_launch(void* const* d_in, const int* in_sizes, int n_in,
                              void* d_out, int out_size, void* d_ws, size_t ws_size,
                              hipStream_t stream) {
    const float* x  = (const float*)d_in[0];
    const float* Wl = (const float*)d_in[1];
    const float* Wr = (const float*)d_in[2];
    const float* b  = (const float*)d_in[3];
    const int*   ei = (const int*)d_in[4];
    const int* src = ei;
    const int* dst = ei + N_EDGES;
    float* out = (float*)d_out;

    char* ws = (char*)d_ws;
    int* deg     = (int*)(ws + 0);                 // 50048 ints
    int* cursor  = (int*)(ws + 200192);            // 50048 ints
    int* rowptr  = (int*)(ws + 400384);            // 50052 ints
    int* csr_src = (int*)(ws + 600592);            // 600064 ints
    unsigned short* Bt_hi = (unsigned short*)(ws + 3000848);   // 256 KB
    unsigned short* Bt_lo = (unsigned short*)(ws + 3262992);   // 256 KB
    unsigned short* x_bf  = (unsigned short*)(ws + 3525136);   // 12.8 MB
    unsigned short* h1    = (unsigned short*)(ws + 16325136);  // 12.8 MB
    unsigned short* h2    = (unsigned short*)(ws + 29125136);  // 12.8 MB

    hipMemsetAsync(deg, 0, 2 * 200192, stream);  // deg + cursor

    deg_hist_kernel<<<(N_EDGES + 255) / 256, 256, 0, stream>>>(dst, deg);
    scan_kernel<<<1, 1024, 0, stream>>>(deg, rowptr);
    fill_kernel<<<(N_EDGES + 255) / 256, 256, 0, stream>>>(src, dst, rowptr, cursor, csr_src);
    convert_x_kernel<<<(N_NODES * DIM / 4 + 255) / 256, 256, 0, stream>>>(x, x_bf);
    prep_w_kernel<<<(4 * 256 * 128 + 255) / 256, 256, 0, stream>>>(Wl, Wr, Bt_hi, Bt_lo);

    const int nblk = (N_NODES + 63) / 64;  // 782
    const unsigned short* hin = x_bf;
    unsigned short* houts_bf[4] = { h1, h2, h1, nullptr };

    for (int l = 0; l < 4; l++) {
        int fin = (l == 3) ? 1 : 0;
        sage_layer_kernel<<<nblk, 256, 0, stream>>>(
            rowptr, csr_src, hin,
            Bt_hi + (size_t)l * 32768, Bt_lo + (size_t)l * 32768, b + (size_t)l * DIM,
            houts_bf[l], out, fin);
        hin = houts_bf[l];
    }
}

// Round 4
// 647.725 us; speedup vs baseline: 1.1763x; 1.1763x over previous
//
#include <hip/hip_runtime.h>

#define N_NODES 50000
#define N_EDGES 600000
#define DIM     128

typedef __attribute__((ext_vector_type(8))) short short8b;  // 8 bf16
typedef __attribute__((ext_vector_type(4))) float f32x4;

__device__ inline unsigned short f2bf(float f) {
    unsigned int u = __builtin_bit_cast(unsigned int, f);
    unsigned int r = (u + 0x7FFFu + ((u >> 16) & 1u)) >> 16;
    return (unsigned short)r;
}
__device__ inline float bf2f(unsigned short b) {
    unsigned int u = ((unsigned int)b) << 16;
    return __builtin_bit_cast(float, u);
}

// ---------------------------------------------------------------------------
// CSR build
// ---------------------------------------------------------------------------
__global__ void deg_hist_kernel(const int* __restrict__ dst, int* __restrict__ deg) {
    int e = blockIdx.x * blockDim.x + threadIdx.x;
    if (e < N_EDGES) atomicAdd(&deg[dst[e]], 1);
}

__global__ __launch_bounds__(1024) void scan_kernel(const int* __restrict__ deg,
                                                    int* __restrict__ rowptr) {
    __shared__ int part[1024];
    const int CH = (N_NODES + 1023) / 1024;  // 49
    int t = threadIdx.x;
    int start = t * CH;
    int end   = min(start + CH, N_NODES);
    int s = 0;
    for (int i = start; i < end; i++) s += deg[i];
    part[t] = s;
    __syncthreads();
    for (int off = 1; off < 1024; off <<= 1) {
        int u = (t >= off) ? part[t - off] : 0;
        __syncthreads();
        part[t] += u;
        __syncthreads();
    }
    int run = part[t] - s;  // exclusive prefix
    for (int i = start; i < end; i++) {
        rowptr[i] = run;
        run += deg[i];
    }
    if (t == 1023) rowptr[N_NODES] = run;
}

__global__ void fill_kernel(const int* __restrict__ src, const int* __restrict__ dst,
                            const int* __restrict__ rowptr, int* __restrict__ cursor,
                            int* __restrict__ csr_src) {
    int e = blockIdx.x * blockDim.x + threadIdx.x;
    if (e >= N_EDGES) return;
    int d = dst[e];
    int pos = rowptr[d] + atomicAdd(&cursor[d], 1);
    csr_src[pos] = src[e];
}

// ---------------------------------------------------------------------------
// x (fp32) -> bf16
// ---------------------------------------------------------------------------
__global__ void convert_x_kernel(const float* __restrict__ x, unsigned short* __restrict__ xb) {
    int i = blockIdx.x * blockDim.x + threadIdx.x;  // 4 elems/thread
    const float4 v = *(const float4*)&x[(size_t)i * 4];
    ushort4 o;
    o.x = f2bf(v.x); o.y = f2bf(v.y); o.z = f2bf(v.z); o.w = f2bf(v.w);
    *(ushort4*)&xb[(size_t)i * 4] = o;
}

// ---------------------------------------------------------------------------
// Weight prep: for each layer l and mat (0=Wl,1=Wr), produce transposed bf16
// hi/lo pair. Layout: Bt[((l*4 + mat*2 + hilo)*128 + c)*128 + k], k contiguous.
// ---------------------------------------------------------------------------
__global__ void prep_w_kernel(const float* __restrict__ Wl, const float* __restrict__ Wr,
                              unsigned short* __restrict__ Bt) {
    int idx = blockIdx.x * blockDim.x + threadIdx.x;  // 4*2*128*128
    if (idx >= 4 * 2 * 128 * 128) return;
    int l   = idx >> 15;
    int mat = (idx >> 14) & 1;
    int k   = (idx >> 7) & 127;
    int c   = idx & 127;
    const float* W = mat ? Wr : Wl;
    float w = W[l * 16384 + k * 128 + c];
    unsigned short hi = f2bf(w);
    float res = w - bf2f(hi);
    unsigned short lo = f2bf(res);
    size_t base = ((size_t)(l * 4 + mat * 2) * 128 + c) * 128 + k;
    Bt[base]         = hi;
    Bt[base + 16384] = lo;
}

// ---------------------------------------------------------------------------
// Dense dual-GEMM: y = bf16(h @ Wl), z = fp32(h @ Wr + b).
// 256 threads = 4 waves; BM=64 (wave w -> 16 rows). A-frags direct from
// global (h rows L1/L2-resident), B hi/lo frags streamed from L2.
// ---------------------------------------------------------------------------
__global__ __launch_bounds__(256) void gemm_kernel(
    const unsigned short* __restrict__ h,   // [N][128] bf16
    const unsigned short* __restrict__ Bt,  // this layer: [4][128][128] bf16
    const float* __restrict__ bias,
    unsigned short* __restrict__ y,         // [N][128] bf16
    float* __restrict__ z)                  // [N][128] fp32 (d_out)
{
    int t = threadIdx.x;
    int lane = t & 63, w = t >> 6;
    int r16 = lane & 15, kg = lane >> 4;
    int rowA  = blockIdx.x * 64 + w * 16 + r16;
    int rowAc = min(rowA, N_NODES - 1);

    f32x4 accY[8], accZ[8];
    #pragma unroll
    for (int ct = 0; ct < 8; ct++) {
        accY[ct] = (f32x4){0.f, 0.f, 0.f, 0.f};
        accZ[ct] = (f32x4){0.f, 0.f, 0.f, 0.f};
    }

    #pragma unroll
    for (int kk = 0; kk < 4; kk++) {
        int k = kg * 8 + kk * 32;
        short8b a = *(const short8b*)&h[(size_t)rowAc * DIM + k];
        #pragma unroll
        for (int ct = 0; ct < 8; ct++) {
            size_t bo = (size_t)(ct * 16 + r16) * 128 + k;
            short8b b0 = *(const short8b*)&Bt[bo];            // Wl hi
            short8b b1 = *(const short8b*)&Bt[16384 + bo];    // Wl lo
            short8b b2 = *(const short8b*)&Bt[32768 + bo];    // Wr hi
            short8b b3 = *(const short8b*)&Bt[49152 + bo];    // Wr lo
            accY[ct] = __builtin_amdgcn_mfma_f32_16x16x32_bf16(a, b0, accY[ct], 0, 0, 0);
            accY[ct] = __builtin_amdgcn_mfma_f32_16x16x32_bf16(a, b1, accY[ct], 0, 0, 0);
            accZ[ct] = __builtin_amdgcn_mfma_f32_16x16x32_bf16(a, b2, accZ[ct], 0, 0, 0);
            accZ[ct] = __builtin_amdgcn_mfma_f32_16x16x32_bf16(a, b3, accZ[ct], 0, 0, 0);
        }
    }

    int rowC0 = blockIdx.x * 64 + w * 16 + kg * 4;
    #pragma unroll
    for (int ct = 0; ct < 8; ct++) {
        int col = ct * 16 + r16;
        float bb = bias[col];
        #pragma unroll
        for (int j = 0; j < 4; j++) {
            int grow = rowC0 + j;
            if (grow < N_NODES) {
                y[(size_t)grow * DIM + col] = f2bf(accY[ct][j]);
                z[(size_t)grow * DIM + col] = accZ[ct][j] + bb;
            }
        }
    }
}

// ---------------------------------------------------------------------------
// Gather/finish: hout = relu(invdeg * sum_{nbr} y[nbr] + z).
// One 64-lane wave per node (2 dims/lane), 4-way unrolled neighbor loop for
// MLP, zero LDS -> full occupancy, 8192-wave TLP.
// ---------------------------------------------------------------------------
__global__ __launch_bounds__(256) void gather_kernel(
    const int* __restrict__ rowptr, const int* __restrict__ csr_src,
    const unsigned short* __restrict__ y, const float* __restrict__ z,
    unsigned short* __restrict__ hout_bf, float* __restrict__ out_f32,
    int final_layer)
{
    int lane = threadIdx.x & 63;
    int gw = blockIdx.x * 4 + (threadIdx.x >> 6);
    int stride = gridDim.x * 4;
    int d2 = lane * 2;

    for (int node = gw; node < N_NODES; node += stride) {
        int beg = rowptr[node], end = rowptr[node + 1];
        float a0 = 0.f, a1 = 0.f;
        int i = beg;
        for (; i + 3 < end; i += 4) {
            int s0 = csr_src[i + 0];
            int s1 = csr_src[i + 1];
            int s2 = csr_src[i + 2];
            int s3 = csr_src[i + 3];
            unsigned int u0 = *(const unsigned int*)&y[(size_t)s0 * DIM + d2];
            unsigned int u1 = *(const unsigned int*)&y[(size_t)s1 * DIM + d2];
            unsigned int u2 = *(const unsigned int*)&y[(size_t)s2 * DIM + d2];
            unsigned int u3 = *(const unsigned int*)&y[(size_t)s3 * DIM + d2];
            a0 += __builtin_bit_cast(float, u0 << 16) + __builtin_bit_cast(float, u1 << 16)
                + __builtin_bit_cast(float, u2 << 16) + __builtin_bit_cast(float, u3 << 16);
            a1 += __builtin_bit_cast(float, u0 & 0xffff0000u) + __builtin_bit_cast(float, u1 & 0xffff0000u)
                + __builtin_bit_cast(float, u2 & 0xffff0000u) + __builtin_bit_cast(float, u3 & 0xffff0000u);
        }
        for (; i < end; i++) {
            int s = csr_src[i];
            unsigned int u = *(const unsigned int*)&y[(size_t)s * DIM + d2];
            a0 += __builtin_bit_cast(float, u << 16);
            a1 += __builtin_bit_cast(float, u & 0xffff0000u);
        }
        float sc = 1.0f / fmaxf((float)(end - beg), 1.0f);
        const float2 zz = *(const float2*)&z[(size_t)node * DIM + d2];
        float v0 = fmaxf(a0 * sc + zz.x, 0.f);
        float v1 = fmaxf(a1 * sc + zz.y, 0.f);
        if (final_layer) {
            float2 o = { v0, v1 };
            *(float2*)&out_f32[(size_t)node * DIM + d2] = o;
        } else {
            ushort2 o = { f2bf(v0), f2bf(v1) };
            *(ushort2*)&hout_bf[(size_t)node * DIM + d2] = o;
        }
    }
}

// ---------------------------------------------------------------------------
// Launch
// ---------------------------------------------------------------------------
extern "C" void kernel_launch(void* const* d_in, const int* in_sizes, int n_in,
                              void* d_out, int out_size, void* d_ws, size_t ws_size,
                              hipStream_t stream) {
    const float* x  = (const float*)d_in[0];
    const float* Wl = (const float*)d_in[1];
    const float* Wr = (const float*)d_in[2];
    const float* b  = (const float*)d_in[3];
    const int*   ei = (const int*)d_in[4];
    const int* src = ei;
    const int* dst = ei + N_EDGES;
    float* out = (float*)d_out;

    char* ws = (char*)d_ws;
    int* deg     = (int*)(ws + 0);                 // 50048 ints
    int* cursor  = (int*)(ws + 200192);            // 50048 ints
    int* rowptr  = (int*)(ws + 400384);            // 50052 ints
    int* csr_src = (int*)(ws + 600592);            // 600064 ints
    unsigned short* Bt   = (unsigned short*)(ws + 3000848);   // 512 KB
    unsigned short* x_bf = (unsigned short*)(ws + 3525136);   // 12.8 MB
    unsigned short* h1   = (unsigned short*)(ws + 16325136);  // 12.8 MB
    unsigned short* ybuf = (unsigned short*)(ws + 29125136);  // 12.8 MB

    hipMemsetAsync(deg, 0, 400384, stream);  // deg + cursor

    deg_hist_kernel<<<(N_EDGES + 255) / 256, 256, 0, stream>>>(dst, deg);
    scan_kernel<<<1, 1024, 0, stream>>>(deg, rowptr);
    fill_kernel<<<(N_EDGES + 255) / 256, 256, 0, stream>>>(src, dst, rowptr, cursor, csr_src);
    convert_x_kernel<<<(N_NODES * DIM / 4 + 255) / 256, 256, 0, stream>>>(x, x_bf);
    prep_w_kernel<<<(4 * 2 * 128 * 128 + 255) / 256, 256, 0, stream>>>(Wl, Wr, Bt);

    const int gemm_blk   = (N_NODES + 63) / 64;   // 782
    const int gather_blk = 2048;                  // 8192 waves

    const unsigned short* hin = x_bf;
    unsigned short* houts[4] = { h1, x_bf, h1, nullptr };

    for (int l = 0; l < 4; l++) {
        int fin = (l == 3) ? 1 : 0;
        gemm_kernel<<<gemm_blk, 256, 0, stream>>>(
            hin, Bt + (size_t)l * 4 * 16384, b + (size_t)l * DIM, ybuf, out);
        gather_kernel<<<gather_blk, 256, 0, stream>>>(
            rowptr, csr_src, ybuf, out, houts[l], out, fin);
        hin = houts[l];
    }
}

// Round 5
// 563.070 us; speedup vs baseline: 1.3532x; 1.1503x over previous
//
#include <hip/hip_runtime.h>

#define N_NODES 50000
#define N_EDGES 600000
#define DIM     128
#define NSB     196   // scan blocks = ceil(50000/256)

typedef __attribute__((ext_vector_type(8))) short short8b;  // 8 bf16
typedef __attribute__((ext_vector_type(4))) float f32x4;

__device__ inline unsigned short f2bf(float f) {
    unsigned int u = __builtin_bit_cast(unsigned int, f);
    unsigned int r = (u + 0x7FFFu + ((u >> 16) & 1u)) >> 16;
    return (unsigned short)r;
}
__device__ inline float bf2f(unsigned short b) {
    unsigned int u = ((unsigned int)b) << 16;
    return __builtin_bit_cast(float, u);
}

// ---------------------------------------------------------------------------
// CSR build
// ---------------------------------------------------------------------------
__global__ void deg_hist_kernel(const int* __restrict__ dst, int* __restrict__ deg) {
    int e = blockIdx.x * blockDim.x + threadIdx.x;
    if (e < N_EDGES) atomicAdd(&deg[dst[e]], 1);
}

// scan step 1: per-block (256-elem chunk) sums
__global__ __launch_bounds__(256) void scan_partial_kernel(const int* __restrict__ deg,
                                                           int* __restrict__ part) {
    __shared__ int s[256];
    int t = threadIdx.x;
    int i = blockIdx.x * 256 + t;
    s[t] = (i < N_NODES) ? deg[i] : 0;
    __syncthreads();
    for (int off = 128; off > 0; off >>= 1) {
        if (t < off) s[t] += s[t + off];
        __syncthreads();
    }
    if (t == 0) part[blockIdx.x] = s[0];
}

// scan step 2: single small block scans the partials -> exclusive block offsets
__global__ __launch_bounds__(256) void scan_offsets_kernel(const int* __restrict__ part,
                                                           int* __restrict__ bofs) {
    __shared__ int s[256];
    int t = threadIdx.x;
    int v = (t < NSB) ? part[t] : 0;
    s[t] = v;
    __syncthreads();
    for (int off = 1; off < 256; off <<= 1) {
        int u = (t >= off) ? s[t - off] : 0;
        __syncthreads();
        s[t] += u;
        __syncthreads();
    }
    bofs[t] = s[t] - v;  // exclusive
}

// scan step 3: per-chunk inclusive scan + block offset -> exclusive rowptr
__global__ __launch_bounds__(256) void scan_final_kernel(const int* __restrict__ deg,
                                                         const int* __restrict__ bofs,
                                                         int* __restrict__ rowptr) {
    __shared__ int s[256];
    int t = threadIdx.x;
    int i = blockIdx.x * 256 + t;
    int v = (i < N_NODES) ? deg[i] : 0;
    s[t] = v;
    __syncthreads();
    for (int off = 1; off < 256; off <<= 1) {
        int u = (t >= off) ? s[t - off] : 0;
        __syncthreads();
        s[t] += u;
        __syncthreads();
    }
    int ex = bofs[blockIdx.x] + s[t] - v;
    if (i < N_NODES) rowptr[i] = ex;
    if (i == N_NODES - 1) rowptr[N_NODES] = ex + v;
}

__global__ void fill_kernel(const int* __restrict__ src, const int* __restrict__ dst,
                            const int* __restrict__ rowptr, int* __restrict__ cursor,
                            int* __restrict__ csr_src) {
    int e = blockIdx.x * blockDim.x + threadIdx.x;
    if (e >= N_EDGES) return;
    int d = dst[e];
    int pos = rowptr[d] + atomicAdd(&cursor[d], 1);
    csr_src[pos] = src[e];
}

// ---------------------------------------------------------------------------
// x (fp32) -> bf16
// ---------------------------------------------------------------------------
__global__ void convert_x_kernel(const float* __restrict__ x, unsigned short* __restrict__ xb) {
    int i = blockIdx.x * blockDim.x + threadIdx.x;  // 4 elems/thread
    const float4 v = *(const float4*)&x[(size_t)i * 4];
    ushort4 o;
    o.x = f2bf(v.x); o.y = f2bf(v.y); o.z = f2bf(v.z); o.w = f2bf(v.w);
    *(ushort4*)&xb[(size_t)i * 4] = o;
}

// ---------------------------------------------------------------------------
// Weight prep: for each layer l and mat (0=Wl,1=Wr), produce transposed bf16
// hi/lo pair. Layout: Bt[((l*4 + mat*2 + hilo)*128 + c)*128 + k], k contiguous.
// ---------------------------------------------------------------------------
__global__ void prep_w_kernel(const float* __restrict__ Wl, const float* __restrict__ Wr,
                              unsigned short* __restrict__ Bt) {
    int idx = blockIdx.x * blockDim.x + threadIdx.x;  // 4*2*128*128
    if (idx >= 4 * 2 * 128 * 128) return;
    int l   = idx >> 15;
    int mat = (idx >> 14) & 1;
    int k   = (idx >> 7) & 127;
    int c   = idx & 127;
    const float* W = mat ? Wr : Wl;
    float w = W[l * 16384 + k * 128 + c];
    unsigned short hi = f2bf(w);
    float res = w - bf2f(hi);
    unsigned short lo = f2bf(res);
    size_t base = ((size_t)(l * 4 + mat * 2) * 128 + c) * 128 + k;
    Bt[base]         = hi;
    Bt[base + 16384] = lo;
}

// ---------------------------------------------------------------------------
// Dense dual-GEMM: y = bf16(h @ Wl), z = fp32(h @ Wr + b).
// ---------------------------------------------------------------------------
__global__ __launch_bounds__(256) void gemm_kernel(
    const unsigned short* __restrict__ h,   // [N][128] bf16
    const unsigned short* __restrict__ Bt,  // this layer: [4][128][128] bf16
    const float* __restrict__ bias,
    unsigned short* __restrict__ y,         // [N][128] bf16
    float* __restrict__ z)                  // [N][128] fp32 (d_out)
{
    int t = threadIdx.x;
    int lane = t & 63, w = t >> 6;
    int r16 = lane & 15, kg = lane >> 4;
    int rowA  = blockIdx.x * 64 + w * 16 + r16;
    int rowAc = min(rowA, N_NODES - 1);

    f32x4 accY[8], accZ[8];
    #pragma unroll
    for (int ct = 0; ct < 8; ct++) {
        accY[ct] = (f32x4){0.f, 0.f, 0.f, 0.f};
        accZ[ct] = (f32x4){0.f, 0.f, 0.f, 0.f};
    }

    #pragma unroll
    for (int kk = 0; kk < 4; kk++) {
        int k = kg * 8 + kk * 32;
        short8b a = *(const short8b*)&h[(size_t)rowAc * DIM + k];
        #pragma unroll
        for (int ct = 0; ct < 8; ct++) {
            size_t bo = (size_t)(ct * 16 + r16) * 128 + k;
            short8b b0 = *(const short8b*)&Bt[bo];            // Wl hi
            short8b b1 = *(const short8b*)&Bt[16384 + bo];    // Wl lo
            short8b b2 = *(const short8b*)&Bt[32768 + bo];    // Wr hi
            short8b b3 = *(const short8b*)&Bt[49152 + bo];    // Wr lo
            accY[ct] = __builtin_amdgcn_mfma_f32_16x16x32_bf16(a, b0, accY[ct], 0, 0, 0);
            accY[ct] = __builtin_amdgcn_mfma_f32_16x16x32_bf16(a, b1, accY[ct], 0, 0, 0);
            accZ[ct] = __builtin_amdgcn_mfma_f32_16x16x32_bf16(a, b2, accZ[ct], 0, 0, 0);
            accZ[ct] = __builtin_amdgcn_mfma_f32_16x16x32_bf16(a, b3, accZ[ct], 0, 0, 0);
        }
    }

    int rowC0 = blockIdx.x * 64 + w * 16 + kg * 4;
    #pragma unroll
    for (int ct = 0; ct < 8; ct++) {
        int col = ct * 16 + r16;
        float bb = bias[col];
        #pragma unroll
        for (int j = 0; j < 4; j++) {
            int grow = rowC0 + j;
            if (grow < N_NODES) {
                y[(size_t)grow * DIM + col] = f2bf(accY[ct][j]);
                z[(size_t)grow * DIM + col] = accZ[ct][j] + bb;
            }
        }
    }
}

// ---------------------------------------------------------------------------
// Gather/finish: hout = relu(invdeg * sum_{nbr} y[nbr] + z).
// ---------------------------------------------------------------------------
__global__ __launch_bounds__(256) void gather_kernel(
    const int* __restrict__ rowptr, const int* __restrict__ csr_src,
    const unsigned short* __restrict__ y, const float* __restrict__ z,
    unsigned short* __restrict__ hout_bf, float* __restrict__ out_f32,
    int final_layer)
{
    int lane = threadIdx.x & 63;
    int gw = blockIdx.x * 4 + (threadIdx.x >> 6);
    int stride = gridDim.x * 4;
    int d2 = lane * 2;

    for (int node = gw; node < N_NODES; node += stride) {
        int beg = rowptr[node], end = rowptr[node + 1];
        float a0 = 0.f, a1 = 0.f;
        int i = beg;
        for (; i + 3 < end; i += 4) {
            int s0 = csr_src[i + 0];
            int s1 = csr_src[i + 1];
            int s2 = csr_src[i + 2];
            int s3 = csr_src[i + 3];
            unsigned int u0 = *(const unsigned int*)&y[(size_t)s0 * DIM + d2];
            unsigned int u1 = *(const unsigned int*)&y[(size_t)s1 * DIM + d2];
            unsigned int u2 = *(const unsigned int*)&y[(size_t)s2 * DIM + d2];
            unsigned int u3 = *(const unsigned int*)&y[(size_t)s3 * DIM + d2];
            a0 += __builtin_bit_cast(float, u0 << 16) + __builtin_bit_cast(float, u1 << 16)
                + __builtin_bit_cast(float, u2 << 16) + __builtin_bit_cast(float, u3 << 16);
            a1 += __builtin_bit_cast(float, u0 & 0xffff0000u) + __builtin_bit_cast(float, u1 & 0xffff0000u)
                + __builtin_bit_cast(float, u2 & 0xffff0000u) + __builtin_bit_cast(float, u3 & 0xffff0000u);
        }
        for (; i < end; i++) {
            int s = csr_src[i];
            unsigned int u = *(const unsigned int*)&y[(size_t)s * DIM + d2];
            a0 += __builtin_bit_cast(float, u << 16);
            a1 += __builtin_bit_cast(float, u & 0xffff0000u);
        }
        float sc = 1.0f / fmaxf((float)(end - beg), 1.0f);
        const float2 zz = *(const float2*)&z[(size_t)node * DIM + d2];
        float v0 = fmaxf(a0 * sc + zz.x, 0.f);
        float v1 = fmaxf(a1 * sc + zz.y, 0.f);
        if (final_layer) {
            float2 o = { v0, v1 };
            *(float2*)&out_f32[(size_t)node * DIM + d2] = o;
        } else {
            ushort2 o = { f2bf(v0), f2bf(v1) };
            *(ushort2*)&hout_bf[(size_t)node * DIM + d2] = o;
        }
    }
}

// ---------------------------------------------------------------------------
// Launch
// ---------------------------------------------------------------------------
extern "C" void kernel_launch(void* const* d_in, const int* in_sizes, int n_in,
                              void* d_out, int out_size, void* d_ws, size_t ws_size,
                              hipStream_t stream) {
    const float* x  = (const float*)d_in[0];
    const float* Wl = (const float*)d_in[1];
    const float* Wr = (const float*)d_in[2];
    const float* b  = (const float*)d_in[3];
    const int*   ei = (const int*)d_in[4];
    const int* src = ei;
    const int* dst = ei + N_EDGES;
    float* out = (float*)d_out;

    char* ws = (char*)d_ws;
    int* deg     = (int*)(ws + 0);                 // 50048 ints
    int* cursor  = (int*)(ws + 200192);            // 50048 ints
    int* rowptr  = (int*)(ws + 400384);            // 50052 ints
    int* csr_src = (int*)(ws + 600592);            // 600064 ints -> ends 3000848
    int* part    = (int*)(ws + 3000848);           // 256 ints
    int* bofs    = (int*)(ws + 3001872);           // 256 ints
    unsigned short* Bt   = (unsigned short*)(ws + 3003136);   // 512 KB
    unsigned short* x_bf = (unsigned short*)(ws + 3527680);   // 12.8 MB
    unsigned short* h1   = (unsigned short*)(ws + 16327936);  // 12.8 MB
    unsigned short* ybuf = (unsigned short*)(ws + 29128192);  // 12.8 MB

    hipMemsetAsync(deg, 0, 400384, stream);  // deg + cursor

    deg_hist_kernel<<<(N_EDGES + 255) / 256, 256, 0, stream>>>(dst, deg);
    scan_partial_kernel<<<NSB, 256, 0, stream>>>(deg, part);
    scan_offsets_kernel<<<1, 256, 0, stream>>>(part, bofs);
    scan_final_kernel<<<NSB, 256, 0, stream>>>(deg, bofs, rowptr);
    fill_kernel<<<(N_EDGES + 255) / 256, 256, 0, stream>>>(src, dst, rowptr, cursor, csr_src);
    convert_x_kernel<<<(N_NODES * DIM / 4 + 255) / 256, 256, 0, stream>>>(x, x_bf);
    prep_w_kernel<<<(4 * 2 * 128 * 128 + 255) / 256, 256, 0, stream>>>(Wl, Wr, Bt);

    const int gemm_blk   = (N_NODES + 63) / 64;   // 782
    const int gather_blk = 2048;                  // 8192 waves

    const unsigned short* hin = x_bf;
    unsigned short* houts[4] = { h1, x_bf, h1, nullptr };

    for (int l = 0; l < 4; l++) {
        int fin = (l == 3) ? 1 : 0;
        gemm_kernel<<<gemm_blk, 256, 0, stream>>>(
            hin, Bt + (size_t)l * 4 * 16384, b + (size_t)l * DIM, ybuf, out);
        gather_kernel<<<gather_blk, 256, 0, stream>>>(
            rowptr, csr_src, ybuf, out, houts[l], out, fin);
        hin = houts[l];
    }
}

// Round 7
// 415.519 us; speedup vs baseline: 1.8337x; 1.3551x over previous
//
#include <hip/hip_runtime.h>

#define N_NODES 50000
#define N_EDGES 600000
#define DIM     128
#define NSB     196   // scan blocks = ceil(50000/256)

typedef __attribute__((ext_vector_type(8))) short short8b;  // 8 bf16
typedef __attribute__((ext_vector_type(4))) float f32x4;

__device__ inline unsigned short f2bf(float f) {
    unsigned int u = __builtin_bit_cast(unsigned int, f);
    unsigned int r = (u + 0x7FFFu + ((u >> 16) & 1u)) >> 16;
    return (unsigned short)r;
}
__device__ inline float bf2f(unsigned short b) {
    unsigned int u = ((unsigned int)b) << 16;
    return __builtin_bit_cast(float, u);
}

// ---------------------------------------------------------------------------
// CSR build
// ---------------------------------------------------------------------------
__global__ void deg_hist_kernel(const int* __restrict__ dst, int* __restrict__ deg) {
    int e = blockIdx.x * blockDim.x + threadIdx.x;
    if (e < N_EDGES) atomicAdd(&deg[dst[e]], 1);
}

__global__ __launch_bounds__(256) void scan_partial_kernel(const int* __restrict__ deg,
                                                           int* __restrict__ part) {
    __shared__ int s[256];
    int t = threadIdx.x;
    int i = blockIdx.x * 256 + t;
    s[t] = (i < N_NODES) ? deg[i] : 0;
    __syncthreads();
    for (int off = 128; off > 0; off >>= 1) {
        if (t < off) s[t] += s[t + off];
        __syncthreads();
    }
    if (t == 0) part[blockIdx.x] = s[0];
}

__global__ __launch_bounds__(256) void scan_offsets_kernel(const int* __restrict__ part,
                                                           int* __restrict__ bofs) {
    __shared__ int s[256];
    int t = threadIdx.x;
    int v = (t < NSB) ? part[t] : 0;
    s[t] = v;
    __syncthreads();
    for (int off = 1; off < 256; off <<= 1) {
        int u = (t >= off) ? s[t - off] : 0;
        __syncthreads();
        s[t] += u;
        __syncthreads();
    }
    bofs[t] = s[t] - v;  // exclusive
}

__global__ __launch_bounds__(256) void scan_final_kernel(const int* __restrict__ deg,
                                                         const int* __restrict__ bofs,
                                                         int* __restrict__ rowptr) {
    __shared__ int s[256];
    int t = threadIdx.x;
    int i = blockIdx.x * 256 + t;
    int v = (i < N_NODES) ? deg[i] : 0;
    s[t] = v;
    __syncthreads();
    for (int off = 1; off < 256; off <<= 1) {
        int u = (t >= off) ? s[t - off] : 0;
        __syncthreads();
        s[t] += u;
        __syncthreads();
    }
    int ex = bofs[blockIdx.x] + s[t] - v;
    if (i < N_NODES) rowptr[i] = ex;
    if (i == N_NODES - 1) rowptr[N_NODES] = ex + v;
}

__global__ void fill_kernel(const int* __restrict__ src, const int* __restrict__ dst,
                            const int* __restrict__ rowptr, int* __restrict__ cursor,
                            int* __restrict__ csr_src) {
    int e = blockIdx.x * blockDim.x + threadIdx.x;
    if (e >= N_EDGES) return;
    int d = dst[e];
    int pos = rowptr[d] + atomicAdd(&cursor[d], 1);
    csr_src[pos] = src[e];
}

// ---------------------------------------------------------------------------
// x (fp32) -> bf16
// ---------------------------------------------------------------------------
__global__ void convert_x_kernel(const float* __restrict__ x, unsigned short* __restrict__ xb) {
    int i = blockIdx.x * blockDim.x + threadIdx.x;  // 4 elems/thread
    const float4 v = *(const float4*)&x[(size_t)i * 4];
    ushort4 o;
    o.x = f2bf(v.x); o.y = f2bf(v.y); o.z = f2bf(v.z); o.w = f2bf(v.w);
    *(ushort4*)&xb[(size_t)i * 4] = o;
}

// ---------------------------------------------------------------------------
// Weight prep (transposed bf16 hi/lo): Bt[((l*4 + mat*2 + hilo)*128 + c)*128 + k]
// ---------------------------------------------------------------------------
__global__ void prep_w_kernel(const float* __restrict__ Wl, const float* __restrict__ Wr,
                              unsigned short* __restrict__ Bt) {
    int idx = blockIdx.x * blockDim.x + threadIdx.x;  // 4*2*128*128
    if (idx >= 4 * 2 * 128 * 128) return;
    int l   = idx >> 15;
    int mat = (idx >> 14) & 1;
    int k   = (idx >> 7) & 127;
    int c   = idx & 127;
    const float* W = mat ? Wr : Wl;
    float w = W[l * 16384 + k * 128 + c];
    unsigned short hi = f2bf(w);
    float res = w - bf2f(hi);
    unsigned short lo = f2bf(res);
    size_t base = ((size_t)(l * 4 + mat * 2) * 128 + c) * 128 + k;
    Bt[base]         = hi;
    Bt[base + 16384] = lo;
}

// ---------------------------------------------------------------------------
// Dense dual-GEMM: y = bf16(h @ Wl), z = fp32(h @ Wr + b).
// Block = 256 thr (4 waves), BM = 64. Wave w owns ALL 64 rows x 32 cols
// (4 row-tiles x 2 col-tiles): each B-fragment feeds 4 MFMAs (4x B reuse),
// 48 loads per 128 MFMAs per wave (was 132) -> latency amortized.
// ---------------------------------------------------------------------------
__global__ __launch_bounds__(256) void gemm_kernel(
    const unsigned short* __restrict__ h,   // [N][128] bf16
    const unsigned short* __restrict__ Bt,  // this layer: [4][128][128] bf16
    const float* __restrict__ bias,
    unsigned short* __restrict__ y,         // [N][128] bf16
    float* __restrict__ z)                  // [N][128] fp32 (d_out)
{
    int t = threadIdx.x;
    int lane = t & 63, w = t >> 6;
    int r16 = lane & 15, kg = lane >> 4;
    int row0 = blockIdx.x * 64;
    int colbase = w * 32;   // wave's 32-col slab: col tiles w*2, w*2+1

    f32x4 accY[4][2], accZ[4][2];
    #pragma unroll
    for (int rt = 0; rt < 4; rt++)
        #pragma unroll
        for (int c = 0; c < 2; c++) {
            accY[rt][c] = (f32x4){0.f, 0.f, 0.f, 0.f};
            accZ[rt][c] = (f32x4){0.f, 0.f, 0.f, 0.f};
        }

    #pragma unroll
    for (int kk = 0; kk < 4; kk++) {
        int k = kg * 8 + kk * 32;
        short8b a[4];
        #pragma unroll
        for (int rt = 0; rt < 4; rt++) {
            int row = min(row0 + rt * 16 + r16, N_NODES - 1);
            a[rt] = *(const short8b*)&h[(size_t)row * DIM + k];
        }
        #pragma unroll
        for (int c = 0; c < 2; c++) {
            size_t bo = (size_t)(colbase + c * 16 + r16) * 128 + k;
            short8b b0 = *(const short8b*)&Bt[bo];            // Wl hi
            short8b b1 = *(const short8b*)&Bt[16384 + bo];    // Wl lo
            short8b b2 = *(const short8b*)&Bt[32768 + bo];    // Wr hi
            short8b b3 = *(const short8b*)&Bt[49152 + bo];    // Wr lo
            #pragma unroll
            for (int rt = 0; rt < 4; rt++) {
                accY[rt][c] = __builtin_amdgcn_mfma_f32_16x16x32_bf16(a[rt], b0, accY[rt][c], 0, 0, 0);
                accY[rt][c] = __builtin_amdgcn_mfma_f32_16x16x32_bf16(a[rt], b1, accY[rt][c], 0, 0, 0);
                accZ[rt][c] = __builtin_amdgcn_mfma_f32_16x16x32_bf16(a[rt], b2, accZ[rt][c], 0, 0, 0);
                accZ[rt][c] = __builtin_amdgcn_mfma_f32_16x16x32_bf16(a[rt], b3, accZ[rt][c], 0, 0, 0);
            }
        }
    }

    #pragma unroll
    for (int rt = 0; rt < 4; rt++) {
        #pragma unroll
        for (int c = 0; c < 2; c++) {
            int col = colbase + c * 16 + r16;
            float bb = bias[col];
            #pragma unroll
            for (int j = 0; j < 4; j++) {
                int grow = row0 + rt * 16 + kg * 4 + j;
                if (grow < N_NODES) {
                    y[(size_t)grow * DIM + col] = f2bf(accY[rt][c][j]);
                    z[(size_t)grow * DIM + col] = accZ[rt][c][j] + bb;
                }
            }
        }
    }
}

// ---------------------------------------------------------------------------
// Gather/finish: hout = relu(invdeg * sum_{nbr} y[nbr] + z).
// ---------------------------------------------------------------------------
__global__ __launch_bounds__(256) void gather_kernel(
    const int* __restrict__ rowptr, const int* __restrict__ csr_src,
    const unsigned short* __restrict__ y, const float* __restrict__ z,
    unsigned short* __restrict__ hout_bf, float* __restrict__ out_f32,
    int final_layer)
{
    int lane = threadIdx.x & 63;
    int gw = blockIdx.x * 4 + (threadIdx.x >> 6);
    int stride = gridDim.x * 4;
    int d2 = lane * 2;

    for (int node = gw; node < N_NODES; node += stride) {
        int beg = rowptr[node], end = rowptr[node + 1];
        float a0 = 0.f, a1 = 0.f;
        int i = beg;
        for (; i + 3 < end; i += 4) {
            int s0 = csr_src[i + 0];
            int s1 = csr_src[i + 1];
            int s2 = csr_src[i + 2];
            int s3 = csr_src[i + 3];
            unsigned int u0 = *(const unsigned int*)&y[(size_t)s0 * DIM + d2];
            unsigned int u1 = *(const unsigned int*)&y[(size_t)s1 * DIM + d2];
            unsigned int u2 = *(const unsigned int*)&y[(size_t)s2 * DIM + d2];
            unsigned int u3 = *(const unsigned int*)&y[(size_t)s3 * DIM + d2];
            a0 += __builtin_bit_cast(float, u0 << 16) + __builtin_bit_cast(float, u1 << 16)
                + __builtin_bit_cast(float, u2 << 16) + __builtin_bit_cast(float, u3 << 16);
            a1 += __builtin_bit_cast(float, u0 & 0xffff0000u) + __builtin_bit_cast(float, u1 & 0xffff0000u)
                + __builtin_bit_cast(float, u2 & 0xffff0000u) + __builtin_bit_cast(float, u3 & 0xffff0000u);
        }
        for (; i < end; i++) {
            int s = csr_src[i];
            unsigned int u = *(const unsigned int*)&y[(size_t)s * DIM + d2];
            a0 += __builtin_bit_cast(float, u << 16);
            a1 += __builtin_bit_cast(float, u & 0xffff0000u);
        }
        float sc = 1.0f / fmaxf((float)(end - beg), 1.0f);
        const float2 zz = *(const float2*)&z[(size_t)node * DIM + d2];
        float v0 = fmaxf(a0 * sc + zz.x, 0.f);
        float v1 = fmaxf(a1 * sc + zz.y, 0.f);
        if (final_layer) {
            float2 o = { v0, v1 };
            *(float2*)&out_f32[(size_t)node * DIM + d2] = o;
        } else {
            ushort2 o = { f2bf(v0), f2bf(v1) };
            *(ushort2*)&hout_bf[(size_t)node * DIM + d2] = o;
        }
    }
}

// ---------------------------------------------------------------------------
// Launch
// ---------------------------------------------------------------------------
extern "C" void kernel_launch(void* const* d_in, const int* in_sizes, int n_in,
                              void* d_out, int out_size, void* d_ws, size_t ws_size,
                              hipStream_t stream) {
    const float* x  = (const float*)d_in[0];
    const float* Wl = (const float*)d_in[1];
    const float* Wr = (const float*)d_in[2];
    const float* b  = (const float*)d_in[3];
    const int*   ei = (const int*)d_in[4];
    const int* src = ei;
    const int* dst = ei + N_EDGES;
    float* out = (float*)d_out;

    char* ws = (char*)d_ws;
    int* deg     = (int*)(ws + 0);                 // 50048 ints
    int* cursor  = (int*)(ws + 200192);            // 50048 ints
    int* rowptr  = (int*)(ws + 400384);            // 50052 ints
    int* csr_src = (int*)(ws + 600592);            // 600064 ints -> ends 3000848
    int* part    = (int*)(ws + 3000848);           // 256 ints
    int* bofs    = (int*)(ws + 3001872);           // 256 ints
    unsigned short* Bt   = (unsigned short*)(ws + 3003136);   // 512 KB
    unsigned short* x_bf = (unsigned short*)(ws + 3527680);   // 12.8 MB
    unsigned short* h1   = (unsigned short*)(ws + 16327936);  // 12.8 MB
    unsigned short* ybuf = (unsigned short*)(ws + 29128192);  // 12.8 MB

    hipMemsetAsync(deg, 0, 400384, stream);  // deg + cursor

    deg_hist_kernel<<<(N_EDGES + 255) / 256, 256, 0, stream>>>(dst, deg);
    scan_partial_kernel<<<NSB, 256, 0, stream>>>(deg, part);
    scan_offsets_kernel<<<1, 256, 0, stream>>>(part, bofs);
    scan_final_kernel<<<NSB, 256, 0, stream>>>(deg, bofs, rowptr);
    fill_kernel<<<(N_EDGES + 255) / 256, 256, 0, stream>>>(src, dst, rowptr, cursor, csr_src);
    convert_x_kernel<<<(N_NODES * DIM / 4 + 255) / 256, 256, 0, stream>>>(x, x_bf);
    prep_w_kernel<<<(4 * 2 * 128 * 128 + 255) / 256, 256, 0, stream>>>(Wl, Wr, Bt);

    const int gemm_blk   = (N_NODES + 63) / 64;   // 782
    const int gather_blk = 2048;                  // 8192 waves

    const unsigned short* hin = x_bf;
    unsigned short* houts[4] = { h1, x_bf, h1, nullptr };

    for (int l = 0; l < 4; l++) {
        int fin = (l == 3) ? 1 : 0;
        gemm_kernel<<<gemm_blk, 256, 0, stream>>>(
            hin, Bt + (size_t)l * 4 * 16384, b + (size_t)l * DIM, ybuf, out);
        gather_kernel<<<gather_blk, 256, 0, stream>>>(
            rowptr, csr_src, ybuf, out, houts[l], out, fin);
        hin = houts[l];
    }
}

// Round 14
// 405.232 us; speedup vs baseline: 1.8802x; 1.0254x over previous
//
#include <hip/hip_runtime.h>

#define N_NODES 50000
#define N_EDGES 600000
#define DIM     128
#define NSB     196    // scan blocks = ceil(50000/256)

#define HIST_BLKS 2344 // ceil(600000/256)
#define CONV_BLKS 3125 // 50000*128/8/256 exactly
#define PREP_BLKS 512  // 4*256*128/256

typedef __attribute__((ext_vector_type(8))) short short8b;  // 8 bf16
typedef __attribute__((ext_vector_type(4))) float f32x4;

__device__ inline unsigned short f2bf(float f) {
    unsigned int u = __builtin_bit_cast(unsigned int, f);
    unsigned int r = (u + 0x7FFFu + ((u >> 16) & 1u)) >> 16;
    return (unsigned short)r;
}
__device__ inline float bf2f(unsigned short b) {
    unsigned int u = ((unsigned int)b) << 16;
    return __builtin_bit_cast(float, u);
}

// ---------------------------------------------------------------------------
// Fused setup: [0,HIST) deg histogram | [HIST,+CONV) x->bf16 | [+CONV,+PREP)
// weight transpose+hi/lo split. All three independent; one launch.
// Bt layout per layer (65536 elems): hi at [c*256+k], lo at [32768 + c*256+k],
// k axis = [Wl rows (0..127) | Wr rows (128..255)].
// ---------------------------------------------------------------------------
__global__ __launch_bounds__(256) void setup_kernel(
    const int* __restrict__ dst, int* __restrict__ deg,
    const float* __restrict__ x, unsigned short* __restrict__ xb,
    const float* __restrict__ Wl, const float* __restrict__ Wr,
    unsigned short* __restrict__ Bt) {
    int b = blockIdx.x, t = threadIdx.x;
    if (b < HIST_BLKS) {
        int e = b * 256 + t;
        if (e < N_EDGES) atomicAdd(&deg[dst[e]], 1);
    } else if (b < HIST_BLKS + CONV_BLKS) {
        int i = (b - HIST_BLKS) * 256 + t;   // 8 elems/thread, exact
        size_t base = (size_t)i * 8;
        const float4 v0 = *(const float4*)&x[base];
        const float4 v1 = *(const float4*)&x[base + 4];
        unsigned short o[8] = { f2bf(v0.x), f2bf(v0.y), f2bf(v0.z), f2bf(v0.w),
                                f2bf(v1.x), f2bf(v1.y), f2bf(v1.z), f2bf(v1.w) };
        *(short8b*)&xb[base] = *(short8b*)o;
    } else {
        int idx = (b - HIST_BLKS - CONV_BLKS) * 256 + t;  // 4*256*128 exact
        int l = idx >> 15;
        int k = (idx & 32767) >> 7;   // 0..255
        int c = idx & 127;
        float w = (k < 128) ? Wl[l * 16384 + k * 128 + c]
                            : Wr[l * 16384 + (k - 128) * 128 + c];
        unsigned short hi = f2bf(w);
        unsigned short lo = f2bf(w - bf2f(hi));
        size_t o = (size_t)l * 65536 + (size_t)c * 256 + k;
        Bt[o]         = hi;
        Bt[o + 32768] = lo;
    }
}

// ---------------------------------------------------------------------------
// 3-kernel decoupled scan
// ---------------------------------------------------------------------------
__global__ __launch_bounds__(256) void scan_partial_kernel(const int* __restrict__ deg,
                                                           int* __restrict__ part) {
    __shared__ int s[256];
    int t = threadIdx.x;
    int i = blockIdx.x * 256 + t;
    s[t] = (i < N_NODES) ? deg[i] : 0;
    __syncthreads();
    for (int off = 128; off > 0; off >>= 1) {
        if (t < off) s[t] += s[t + off];
        __syncthreads();
    }
    if (t == 0) part[blockIdx.x] = s[0];
}

__global__ __launch_bounds__(256) void scan_offsets_kernel(const int* __restrict__ part,
                                                           int* __restrict__ bofs) {
    __shared__ int s[256];
    int t = threadIdx.x;
    int v = (t < NSB) ? part[t] : 0;
    s[t] = v;
    __syncthreads();
    for (int off = 1; off < 256; off <<= 1) {
        int u = (t >= off) ? s[t - off] : 0;
        __syncthreads();
        s[t] += u;
        __syncthreads();
    }
    bofs[t] = s[t] - v;  // exclusive
}

__global__ __launch_bounds__(256) void scan_final_kernel(const int* __restrict__ deg,
                                                         const int* __restrict__ bofs,
                                                         int* __restrict__ rowptr) {
    __shared__ int s[256];
    int t = threadIdx.x;
    int i = blockIdx.x * 256 + t;
    int v = (i < N_NODES) ? deg[i] : 0;
    s[t] = v;
    __syncthreads();
    for (int off = 1; off < 256; off <<= 1) {
        int u = (t >= off) ? s[t - off] : 0;
        __syncthreads();
        s[t] += u;
        __syncthreads();
    }
    int ex = bofs[blockIdx.x] + s[t] - v;
    if (i < N_NODES) rowptr[i] = ex;
    if (i == N_NODES - 1) rowptr[N_NODES] = ex + v;
}

__global__ void fill_kernel(const int* __restrict__ src, const int* __restrict__ dst,
                            const int* __restrict__ rowptr, int* __restrict__ cursor,
                            int* __restrict__ csr_src) {
    int e = blockIdx.x * blockDim.x + threadIdx.x;
    if (e >= N_EDGES) return;
    int d = dst[e];
    int pos = rowptr[d] + atomicAdd(&cursor[d], 1);
    csr_src[pos] = src[e];
}

// ---------------------------------------------------------------------------
// Gather: agg[n] = bf16( (1/max(deg,1)) * sum_{s in nbr(n)} h[s] ).
// One wave per node (2 dims/lane), 4-way unrolled for MLP, zero LDS.
// ---------------------------------------------------------------------------
__global__ __launch_bounds__(256) void gather_kernel(
    const int* __restrict__ rowptr, const int* __restrict__ csr_src,
    const unsigned short* __restrict__ h, unsigned short* __restrict__ agg)
{
    int lane = threadIdx.x & 63;
    int gw = blockIdx.x * 4 + (threadIdx.x >> 6);
    int stride = gridDim.x * 4;
    int d2 = lane * 2;

    for (int node = gw; node < N_NODES; node += stride) {
        int beg = rowptr[node], end = rowptr[node + 1];
        float a0 = 0.f, a1 = 0.f;
        int i = beg;
        for (; i + 3 < end; i += 4) {
            int s0 = csr_src[i + 0];
            int s1 = csr_src[i + 1];
            int s2 = csr_src[i + 2];
            int s3 = csr_src[i + 3];
            unsigned int u0 = *(const unsigned int*)&h[(size_t)s0 * DIM + d2];
            unsigned int u1 = *(const unsigned int*)&h[(size_t)s1 * DIM + d2];
            unsigned int u2 = *(const unsigned int*)&h[(size_t)s2 * DIM + d2];
            unsigned int u3 = *(const unsigned int*)&h[(size_t)s3 * DIM + d2];
            a0 += __builtin_bit_cast(float, u0 << 16) + __builtin_bit_cast(float, u1 << 16)
                + __builtin_bit_cast(float, u2 << 16) + __builtin_bit_cast(float, u3 << 16);
            a1 += __builtin_bit_cast(float, u0 & 0xffff0000u) + __builtin_bit_cast(float, u1 & 0xffff0000u)
                + __builtin_bit_cast(float, u2 & 0xffff0000u) + __builtin_bit_cast(float, u3 & 0xffff0000u);
        }
        for (; i < end; i++) {
            int s = csr_src[i];
            unsigned int u = *(const unsigned int*)&h[(size_t)s * DIM + d2];
            a0 += __builtin_bit_cast(float, u << 16);
            a1 += __builtin_bit_cast(float, u & 0xffff0000u);
        }
        float sc = 1.0f / fmaxf((float)(end - beg), 1.0f);
        ushort2 o = { f2bf(a0 * sc), f2bf(a1 * sc) };
        *(ushort2*)&agg[(size_t)node * DIM + d2] = o;
    }
}

// ---------------------------------------------------------------------------
// Single fused SAGE GEMM: out = relu([agg|h] @ [Wl;Wr]_hilo + b).
// Block = 256 thr (4 waves), BM=64. Wave owns 64 rows x 32 cols (4 rt x 2 ct),
// K=256 (kk<4 -> agg, kk>=4 -> h; branch folds at compile time).
// Each B-fragment feeds 4 MFMAs; 128 MFMAs & 64 loads per wave.
// ---------------------------------------------------------------------------
__global__ __launch_bounds__(256) void gemm_kernel(
    const unsigned short* __restrict__ agg,  // [N][128] bf16
    const unsigned short* __restrict__ h,    // [N][128] bf16
    const unsigned short* __restrict__ Bt,   // layer: [2][128][256] bf16 hi/lo
    const float* __restrict__ bias,
    unsigned short* __restrict__ out_bf, float* __restrict__ out_f32,
    int final_layer)
{
    int t = threadIdx.x;
    int lane = t & 63, w = t >> 6;
    int r16 = lane & 15, kg = lane >> 4;
    int row0 = blockIdx.x * 64;
    int colbase = w * 32;

    f32x4 acc[4][2];
    #pragma unroll
    for (int rt = 0; rt < 4; rt++)
        #pragma unroll
        for (int c = 0; c < 2; c++)
            acc[rt][c] = (f32x4){0.f, 0.f, 0.f, 0.f};

    #pragma unroll
    for (int kk = 0; kk < 8; kk++) {
        int k = kg * 8 + kk * 32;                       // 0..255
        const unsigned short* Ab = (kk < 4) ? agg : h;  // compile-time per kk
        int kloc = k - ((kk < 4) ? 0 : 128);
        short8b a[4];
        #pragma unroll
        for (int rt = 0; rt < 4; rt++) {
            int row = min(row0 + rt * 16 + r16, N_NODES - 1);
            a[rt] = *(const short8b*)&Ab[(size_t)row * DIM + kloc];
        }
        #pragma unroll
        for (int c = 0; c < 2; c++) {
            size_t bo = (size_t)(colbase + c * 16 + r16) * 256 + k;
            short8b bh = *(const short8b*)&Bt[bo];
            short8b bl = *(const short8b*)&Bt[32768 + bo];
            #pragma unroll
            for (int rt = 0; rt < 4; rt++) {
                acc[rt][c] = __builtin_amdgcn_mfma_f32_16x16x32_bf16(a[rt], bh, acc[rt][c], 0, 0, 0);
                acc[rt][c] = __builtin_amdgcn_mfma_f32_16x16x32_bf16(a[rt], bl, acc[rt][c], 0, 0, 0);
            }
        }
    }

    #pragma unroll
    for (int rt = 0; rt < 4; rt++) {
        #pragma unroll
        for (int c = 0; c < 2; c++) {
            int col = colbase + c * 16 + r16;
            float bb = bias[col];
            #pragma unroll
            for (int j = 0; j < 4; j++) {
                int grow = row0 + rt * 16 + kg * 4 + j;
                if (grow < N_NODES) {
                    float v = fmaxf(acc[rt][c][j] + bb, 0.f);
                    if (final_layer) out_f32[(size_t)grow * DIM + col] = v;
                    else             out_bf [(size_t)grow * DIM + col] = f2bf(v);
                }
            }
        }
    }
}

// ---------------------------------------------------------------------------
// Launch
// ---------------------------------------------------------------------------
extern "C" void kernel_launch(void* const* d_in, const int* in_sizes, int n_in,
                              void* d_out, int out_size, void* d_ws, size_t ws_size,
                              hipStream_t stream) {
    const float* x  = (const float*)d_in[0];
    const float* Wl = (const float*)d_in[1];
    const float* Wr = (const float*)d_in[2];
    const float* b  = (const float*)d_in[3];
    const int*   ei = (const int*)d_in[4];
    const int* src = ei;
    const int* dst = ei + N_EDGES;
    float* out = (float*)d_out;

    char* ws = (char*)d_ws;
    int* deg     = (int*)(ws + 0);                 // 50048 ints
    int* cursor  = (int*)(ws + 200192);            // 50048 ints
    int* rowptr  = (int*)(ws + 400384);            // 50052 ints
    int* csr_src = (int*)(ws + 600592);            // 600064 ints -> 3000848
    int* part    = (int*)(ws + 3000848);           // 256 ints
    int* bofs    = (int*)(ws + 3001872);           // 256 ints
    unsigned short* Bt   = (unsigned short*)(ws + 3003136);   // 512 KB -> 3527424
    unsigned short* x_bf = (unsigned short*)(ws + 3527680);   // 12.8 MB
    unsigned short* hA   = (unsigned short*)(ws + 16327680);  // 12.8 MB
    unsigned short* hB   = (unsigned short*)(ws + 29127680);  // 12.8 MB
    unsigned short* aggb = (unsigned short*)(ws + 41927680);  // 12.8 MB

    hipMemsetAsync(deg, 0, 400384, stream);  // deg + cursor

    setup_kernel<<<HIST_BLKS + CONV_BLKS + PREP_BLKS, 256, 0, stream>>>(
        dst, deg, x, x_bf, Wl, Wr, Bt);
    scan_partial_kernel<<<NSB, 256, 0, stream>>>(deg, part);
    scan_offsets_kernel<<<1, 256, 0, stream>>>(part, bofs);
    scan_final_kernel<<<NSB, 256, 0, stream>>>(deg, bofs, rowptr);
    fill_kernel<<<HIST_BLKS, 256, 0, stream>>>(src, dst, rowptr, cursor, csr_src);

    const int gemm_blk   = (N_NODES + 63) / 64;   // 782
    const int gather_blk = 2048;                  // 8192 waves

    const unsigned short* hin = x_bf;
    unsigned short* houts[4] = { hA, hB, hA, nullptr };

    for (int l = 0; l < 4; l++) {
        int fin = (l == 3) ? 1 : 0;
        gather_kernel<<<gather_blk, 256, 0, stream>>>(rowptr, csr_src, hin, aggb);
        gemm_kernel<<<gemm_blk, 256, 0, stream>>>(
            aggb, hin, Bt + (size_t)l * 65536, b + (size_t)l * DIM,
            houts[l], out, fin);
        hin = houts[l];
    }
}

// Round 16
// 394.039 us; speedup vs baseline: 1.9336x; 1.0284x over previous
//
#include <hip/hip_runtime.h>

#define N_NODES 50000
#define N_EDGES 600000
#define DIM     128
#define NSB     196    // scan blocks = ceil(50000/256)

#define HIST_BLKS 2344 // ceil(600000/256)
#define CONV_BLKS 3125 // 50000*128/8/256 exactly
#define PREP_BLKS 512  // 4*256*128/256

typedef __attribute__((ext_vector_type(8))) short short8b;  // 8 bf16
typedef __attribute__((ext_vector_type(4))) float f32x4;

__device__ inline unsigned short f2bf(float f) {
    unsigned int u = __builtin_bit_cast(unsigned int, f);
    unsigned int r = (u + 0x7FFFu + ((u >> 16) & 1u)) >> 16;
    return (unsigned short)r;
}
__device__ inline float bf2f(unsigned short b) {
    unsigned int u = ((unsigned int)b) << 16;
    return __builtin_bit_cast(float, u);
}
__device__ inline float bflo(unsigned int u) {
    return __builtin_bit_cast(float, u << 16);
}
__device__ inline float bfhi(unsigned int u) {
    return __builtin_bit_cast(float, u & 0xffff0000u);
}

// ---------------------------------------------------------------------------
// Fused setup: [0,HIST) deg histogram | [HIST,+CONV) x->bf16 | [+CONV,+PREP)
// weight transpose+hi/lo split. Bt layout per layer (65536 elems):
// hi at [c*256+k], lo at [32768 + c*256+k], k = [Wl rows | Wr rows].
// ---------------------------------------------------------------------------
__global__ __launch_bounds__(256) void setup_kernel(
    const int* __restrict__ dst, int* __restrict__ deg,
    const float* __restrict__ x, unsigned short* __restrict__ xb,
    const float* __restrict__ Wl, const float* __restrict__ Wr,
    unsigned short* __restrict__ Bt) {
    int b = blockIdx.x, t = threadIdx.x;
    if (b < HIST_BLKS) {
        int e = b * 256 + t;
        if (e < N_EDGES) atomicAdd(&deg[dst[e]], 1);
    } else if (b < HIST_BLKS + CONV_BLKS) {
        int i = (b - HIST_BLKS) * 256 + t;   // 8 elems/thread, exact
        size_t base = (size_t)i * 8;
        const float4 v0 = *(const float4*)&x[base];
        const float4 v1 = *(const float4*)&x[base + 4];
        unsigned short o[8] = { f2bf(v0.x), f2bf(v0.y), f2bf(v0.z), f2bf(v0.w),
                                f2bf(v1.x), f2bf(v1.y), f2bf(v1.z), f2bf(v1.w) };
        *(short8b*)&xb[base] = *(short8b*)o;
    } else {
        int idx = (b - HIST_BLKS - CONV_BLKS) * 256 + t;  // 4*256*128 exact
        int l = idx >> 15;
        int k = (idx & 32767) >> 7;   // 0..255
        int c = idx & 127;
        float w = (k < 128) ? Wl[l * 16384 + k * 128 + c]
                            : Wr[l * 16384 + (k - 128) * 128 + c];
        unsigned short hi = f2bf(w);
        unsigned short lo = f2bf(w - bf2f(hi));
        size_t o = (size_t)l * 65536 + (size_t)c * 256 + k;
        Bt[o]         = hi;
        Bt[o + 32768] = lo;
    }
}

// ---------------------------------------------------------------------------
// 3-kernel decoupled scan
// ---------------------------------------------------------------------------
__global__ __launch_bounds__(256) void scan_partial_kernel(const int* __restrict__ deg,
                                                           int* __restrict__ part) {
    __shared__ int s[256];
    int t = threadIdx.x;
    int i = blockIdx.x * 256 + t;
    s[t] = (i < N_NODES) ? deg[i] : 0;
    __syncthreads();
    for (int off = 128; off > 0; off >>= 1) {
        if (t < off) s[t] += s[t + off];
        __syncthreads();
    }
    if (t == 0) part[blockIdx.x] = s[0];
}

__global__ __launch_bounds__(256) void scan_offsets_kernel(const int* __restrict__ part,
                                                           int* __restrict__ bofs) {
    __shared__ int s[256];
    int t = threadIdx.x;
    int v = (t < NSB) ? part[t] : 0;
    s[t] = v;
    __syncthreads();
    for (int off = 1; off < 256; off <<= 1) {
        int u = (t >= off) ? s[t - off] : 0;
        __syncthreads();
        s[t] += u;
        __syncthreads();
    }
    bofs[t] = s[t] - v;  // exclusive
}

__global__ __launch_bounds__(256) void scan_final_kernel(const int* __restrict__ deg,
                                                         const int* __restrict__ bofs,
                                                         int* __restrict__ rowptr) {
    __shared__ int s[256];
    int t = threadIdx.x;
    int i = blockIdx.x * 256 + t;
    int v = (i < N_NODES) ? deg[i] : 0;
    s[t] = v;
    __syncthreads();
    for (int off = 1; off < 256; off <<= 1) {
        int u = (t >= off) ? s[t - off] : 0;
        __syncthreads();
        s[t] += u;
        __syncthreads();
    }
    int ex = bofs[blockIdx.x] + s[t] - v;
    if (i < N_NODES) rowptr[i] = ex;
    if (i == N_NODES - 1) rowptr[N_NODES] = ex + v;
}

__global__ void fill_kernel(const int* __restrict__ src, const int* __restrict__ dst,
                            const int* __restrict__ rowptr, int* __restrict__ cursor,
                            int* __restrict__ csr_src) {
    int e = blockIdx.x * blockDim.x + threadIdx.x;
    if (e >= N_EDGES) return;
    int d = dst[e];
    int pos = rowptr[d] + atomicAdd(&cursor[d], 1);
    csr_src[pos] = src[e];
}

// ---------------------------------------------------------------------------
// Gather v2: agg[n] = bf16( (1/max(deg,1)) * sum_{s in nbr(n)} h[s] ).
// One wave per node. Lane layout: grp = lane>>4 (4 neighbor streams),
// sub = lane&15 (dims sub*8..+7, one uint4 = 8 bf16 = 16B per lane).
// Group g sums neighbors i = beg+g, beg+g+4, ... ; cross-group shfl_xor
// reduce (16, 32); group 0 writes the 256B row.
// ---------------------------------------------------------------------------
__global__ __launch_bounds__(256) void gather_kernel(
    const int* __restrict__ rowptr, const int* __restrict__ csr_src,
    const unsigned short* __restrict__ h, unsigned short* __restrict__ agg)
{
    int lane = threadIdx.x & 63;
    int grp  = lane >> 4;        // 0..3
    int sub  = lane & 15;        // 0..15
    int d8   = sub * 8;          // 8 bf16 = 16 B per lane
    int gw = blockIdx.x * 4 + (threadIdx.x >> 6);
    int stride = gridDim.x * 4;

    for (int node = gw; node < N_NODES; node += stride) {
        int beg = rowptr[node], end = rowptr[node + 1];
        float a0 = 0.f, a1 = 0.f, a2 = 0.f, a3 = 0.f;
        float a4 = 0.f, a5 = 0.f, a6 = 0.f, a7 = 0.f;
        for (int i = beg + grp; i < end; i += 4) {
            int s = csr_src[i];
            const uint4 v = *(const uint4*)&h[(size_t)s * DIM + d8];
            a0 += bflo(v.x); a1 += bfhi(v.x);
            a2 += bflo(v.y); a3 += bfhi(v.y);
            a4 += bflo(v.z); a5 += bfhi(v.z);
            a6 += bflo(v.w); a7 += bfhi(v.w);
        }
        // reduce across the 4 groups (lanes ^16, ^32)
        a0 += __shfl_xor(a0, 16); a1 += __shfl_xor(a1, 16);
        a2 += __shfl_xor(a2, 16); a3 += __shfl_xor(a3, 16);
        a4 += __shfl_xor(a4, 16); a5 += __shfl_xor(a5, 16);
        a6 += __shfl_xor(a6, 16); a7 += __shfl_xor(a7, 16);
        a0 += __shfl_xor(a0, 32); a1 += __shfl_xor(a1, 32);
        a2 += __shfl_xor(a2, 32); a3 += __shfl_xor(a3, 32);
        a4 += __shfl_xor(a4, 32); a5 += __shfl_xor(a5, 32);
        a6 += __shfl_xor(a6, 32); a7 += __shfl_xor(a7, 32);

        if (grp == 0) {
            float sc = 1.0f / fmaxf((float)(end - beg), 1.0f);
            unsigned short o[8] = { f2bf(a0 * sc), f2bf(a1 * sc), f2bf(a2 * sc), f2bf(a3 * sc),
                                    f2bf(a4 * sc), f2bf(a5 * sc), f2bf(a6 * sc), f2bf(a7 * sc) };
            *(short8b*)&agg[(size_t)node * DIM + d8] = *(short8b*)o;
        }
    }
}

// ---------------------------------------------------------------------------
// Single fused SAGE GEMM: out = relu([agg|h] @ [Wl;Wr]_hilo + b).
// Block = 256 thr (4 waves), BM=64. Wave owns 64 rows x 32 cols (4 rt x 2 ct),
// K=256 (kk<4 -> agg, kk>=4 -> h). Each B-fragment feeds 4 MFMAs.
// ---------------------------------------------------------------------------
__global__ __launch_bounds__(256) void gemm_kernel(
    const unsigned short* __restrict__ agg,  // [N][128] bf16
    const unsigned short* __restrict__ h,    // [N][128] bf16
    const unsigned short* __restrict__ Bt,   // layer: [2][128][256] bf16 hi/lo
    const float* __restrict__ bias,
    unsigned short* __restrict__ out_bf, float* __restrict__ out_f32,
    int final_layer)
{
    int t = threadIdx.x;
    int lane = t & 63, w = t >> 6;
    int r16 = lane & 15, kg = lane >> 4;
    int row0 = blockIdx.x * 64;
    int colbase = w * 32;

    f32x4 acc[4][2];
    #pragma unroll
    for (int rt = 0; rt < 4; rt++)
        #pragma unroll
        for (int c = 0; c < 2; c++)
            acc[rt][c] = (f32x4){0.f, 0.f, 0.f, 0.f};

    #pragma unroll
    for (int kk = 0; kk < 8; kk++) {
        int k = kg * 8 + kk * 32;                       // 0..255
        const unsigned short* Ab = (kk < 4) ? agg : h;  // compile-time per kk
        int kloc = k - ((kk < 4) ? 0 : 128);
        short8b a[4];
        #pragma unroll
        for (int rt = 0; rt < 4; rt++) {
            int row = min(row0 + rt * 16 + r16, N_NODES - 1);
            a[rt] = *(const short8b*)&Ab[(size_t)row * DIM + kloc];
        }
        #pragma unroll
        for (int c = 0; c < 2; c++) {
            size_t bo = (size_t)(colbase + c * 16 + r16) * 256 + k;
            short8b bh = *(const short8b*)&Bt[bo];
            short8b bl = *(const short8b*)&Bt[32768 + bo];
            #pragma unroll
            for (int rt = 0; rt < 4; rt++) {
                acc[rt][c] = __builtin_amdgcn_mfma_f32_16x16x32_bf16(a[rt], bh, acc[rt][c], 0, 0, 0);
                acc[rt][c] = __builtin_amdgcn_mfma_f32_16x16x32_bf16(a[rt], bl, acc[rt][c], 0, 0, 0);
            }
        }
    }

    #pragma unroll
    for (int rt = 0; rt < 4; rt++) {
        #pragma unroll
        for (int c = 0; c < 2; c++) {
            int col = colbase + c * 16 + r16;
            float bb = bias[col];
            #pragma unroll
            for (int j = 0; j < 4; j++) {
                int grow = row0 + rt * 16 + kg * 4 + j;
                if (grow < N_NODES) {
                    float v = fmaxf(acc[rt][c][j] + bb, 0.f);
                    if (final_layer) out_f32[(size_t)grow * DIM + col] = v;
                    else             out_bf [(size_t)grow * DIM + col] = f2bf(v);
                }
            }
        }
    }
}

// ---------------------------------------------------------------------------
// Launch
// ---------------------------------------------------------------------------
extern "C" void kernel_launch(void* const* d_in, const int* in_sizes, int n_in,
                              void* d_out, int out_size, void* d_ws, size_t ws_size,
                              hipStream_t stream) {
    const float* x  = (const float*)d_in[0];
    const float* Wl = (const float*)d_in[1];
    const float* Wr = (const float*)d_in[2];
    const float* b  = (const float*)d_in[3];
    const int*   ei = (const int*)d_in[4];
    const int* src = ei;
    const int* dst = ei + N_EDGES;
    float* out = (float*)d_out;

    char* ws = (char*)d_ws;
    int* deg     = (int*)(ws + 0);                 // 50048 ints
    int* cursor  = (int*)(ws + 200192);            // 50048 ints
    int* rowptr  = (int*)(ws + 400384);            // 50052 ints
    int* csr_src = (int*)(ws + 600592);            // 600064 ints -> 3000848
    int* part    = (int*)(ws + 3000848);           // 256 ints
    int* bofs    = (int*)(ws + 3001872);           // 256 ints
    unsigned short* Bt   = (unsigned short*)(ws + 3003136);   // 512 KB -> 3527424
    unsigned short* x_bf = (unsigned short*)(ws + 3527680);   // 12.8 MB
    unsigned short* hA   = (unsigned short*)(ws + 16327680);  // 12.8 MB
    unsigned short* hB   = (unsigned short*)(ws + 29127680);  // 12.8 MB
    unsigned short* aggb = (unsigned short*)(ws + 41927680);  // 12.8 MB

    hipMemsetAsync(deg, 0, 400384, stream);  // deg + cursor

    setup_kernel<<<HIST_BLKS + CONV_BLKS + PREP_BLKS, 256, 0, stream>>>(
        dst, deg, x, x_bf, Wl, Wr, Bt);
    scan_partial_kernel<<<NSB, 256, 0, stream>>>(deg, part);
    scan_offsets_kernel<<<1, 256, 0, stream>>>(part, bofs);
    scan_final_kernel<<<NSB, 256, 0, stream>>>(deg, bofs, rowptr);
    fill_kernel<<<HIST_BLKS, 256, 0, stream>>>(src, dst, rowptr, cursor, csr_src);

    const int gemm_blk   = (N_NODES + 63) / 64;   // 782
    const int gather_blk = 2048;                  // 8192 waves

    const unsigned short* hin = x_bf;
    unsigned short* houts[4] = { hA, hB, hA, nullptr };

    for (int l = 0; l < 4; l++) {
        int fin = (l == 3) ? 1 : 0;
        gather_kernel<<<gather_blk, 256, 0, stream>>>(rowptr, csr_src, hin, aggb);
        gemm_kernel<<<gemm_blk, 256, 0, stream>>>(
            aggb, hin, Bt + (size_t)l * 65536, b + (size_t)l * DIM,
            houts[l], out, fin);
        hin = houts[l];
    }
}